// Round 11
// baseline (125.845 us; speedup 1.0000x reference)
//
#include <hip/hip_runtime.h>

// LRMU scan collapsed to a log-doubling chain + Horner epilogue.
// R11 = R6's chain/barrier/data (best measured: 62us = ~11 compute + 8 x
// ~6.3us barriers) truncated at 6 steps (P rows [0,64) + A^64), with
//   out = G0 + (G1 + (G2 + G3@A64)@A64)@A64,
//   Gs  = sum_{j<64} U[255-j-64s] (x) P[j]   (wave s owns Gs).
// Trades 2 barriers (~12.6us, the measured floor per R2-R10 ledger) for
// ~5us of block-local Horner multiplies. R10's hierarchical sc0 barrier
// failed correctness -> R6-exact gbar restored. Data scheme validated
// R5-R9: sc1 write-once stores + normal cached first-touch loads; no
// __threadfence anywhere.

#define SEQ_T 256
#define DIM 128
#define ORD 256
#define BMROWS 2048

// float offsets into ws (write-once buffers, guard gaps)
#define OFF_U 0                                  // U[t][bm]: 256*2048
#define OFF_P (OFF_U + SEQ_T * BMROWS)           // P[j][o]: rows 0..63 used
#define APSTRIDE (ORD * ORD + 2048)
#define OFF_AP (OFF_P + ORD * ORD + 2048)        // AP[k]=A^(2^(k+1)), k=0..5
#define OFF_FLAGS (OFF_AP + 7 * APSTRIDE + 2048) // 256 flags; gen at word 320

#define LD_A(p) \
  __hip_atomic_load((p), __ATOMIC_RELAXED, __HIP_MEMORY_SCOPE_AGENT)
#define ST_A(p, v) \
  __hip_atomic_store((p), (v), __ATOMIC_RELAXED, __HIP_MEMORY_SCOPE_AGENT)

// R6-exact fence-free grid barrier (measured best of R2-R10 variants):
// arrival flags on lines nobody polls; block 0 gathers with 256 parallel
// pollers; single gen word released once; s_sleep(1) everywhere.
__device__ __forceinline__ void gbar(unsigned* flags, unsigned target) {
  asm volatile("s_waitcnt vmcnt(0)" ::: "memory");  // drain this wave's sc1 st
  __syncthreads();  // all waves of the block drained
  const int tid = threadIdx.x;
  if (blockIdx.x == 0) {
    if (tid == 0) ST_A(&flags[0], target);
    while (LD_A(&flags[tid]) < target) __builtin_amdgcn_s_sleep(1);
    __syncthreads();  // all 256 flags seen
    if (tid == 0) ST_A(&flags[320], target);
  } else {
    if (tid == 0) {
      ST_A(&flags[blockIdx.x], target);
      while (LD_A(&flags[320]) < target) __builtin_amdgcn_s_sleep(1);
    }
  }
  __syncthreads();
}

__global__ __launch_bounds__(256) void lrmu_all(
    const float* __restrict__ x, const float* __restrict__ K,
    const float* __restrict__ A, const float* __restrict__ Bm,
    float* __restrict__ out, float* __restrict__ ws) {
  __shared__ __align__(16) float Slds[ORD * 64];  // 64 KB: S slice / Garr+redo
  __shared__ __align__(16) float lsb[5 * ORD];    // 5 KB: chain left rows
  __shared__ __align__(16) float redb[4 * 320];   // 5 KB: chain wave partials
  __shared__ __align__(16) float us[SEQ_T * 8];   // 8 KB: U cols for out
  float* U = ws + OFF_U;
  float* P = ws + OFF_P;
  unsigned* flags = (unsigned*)(ws + OFF_FLAGS);
  const int blk = blockIdx.x, tid = threadIdx.x;

  // ---------- U phase: U[t][bm] = sum_d x[b][t][d] * K[d][m] ----------
  {
    int b = blk >> 4, tc = blk & 15;
    float* xs = Slds;
    for (int idx = tid; idx < 16 * DIM; idx += 256)
      xs[idx] = x[(b * SEQ_T + tc * 16) * DIM + idx];
    __syncthreads();
    int m = tid & 127, th = tid >> 7;
    float acc[8] = {};
#pragma unroll 8
    for (int d = 0; d < DIM; ++d) {
      float kv = K[d * DIM + m];  // coalesced, L2-resident
#pragma unroll
      for (int r = 0; r < 8; ++r)
        acc[r] = fmaf(xs[(th * 8 + r) * DIM + d], kv, acc[r]);
    }
#pragma unroll
    for (int r = 0; r < 8; ++r)  // sc1: read cross-XCD at out phase
      ST_A(&U[(tc * 16 + th * 8 + r) * BMROWS + b * DIM + m], acc[r]);
    if (blk == 0) ST_A(&P[tid], Bm[tid]);  // P[0][:] = b
    __syncthreads();  // before Slds reuse in chain
  }

  // ---------- chain: 6 steps. Step k reads S=A^(2^k); writes S^2 to AP[k]
  // and P[half+rg] = P[rg] @ S (rg < half = 2^k). ----------
  const int rg = blk >> 2, cg = blk & 3;
  const int lane = tid & 63, q = tid >> 6;
  const int ir = lane >> 4, c4 = (lane & 15) * 4;
  for (int k = 0; k < 6; ++k) {
    const float* S = (k == 0) ? A : (ws + OFF_AP + (k - 1) * APSTRIDE);
    float* Snew = ws + OFF_AP + k * APSTRIDE;
    const int half = 1 << k;
    const int ndb = (rg < half) ? 1 : 0;
    const int nrows = 4 + ndb;

    // stage left rows into lsb[5][256]: 4 squaring rows + optional P row
#pragma unroll
    for (int s = 0; s < 5; ++s) {
      float v = 0.f;
      if (s < 4) {
        v = S[(4 * rg + s) * ORD + tid];
      } else if (ndb) {
        v = (k == 0) ? Bm[tid] : P[rg * ORD + tid];  // write-once P rows
      }
      lsb[s * ORD + tid] = v;
    }
    // stage right slice S[:, 64cg..+64) into Slds[256][64] via float4
#pragma unroll
    for (int j = 0; j < 16; ++j) {
      int f = tid + 256 * j;
      int i = f >> 4, cc = (f & 15) * 4;
      *(float4*)&Slds[i * 64 + cc] =
          *(const float4*)&S[i * ORD + cg * 64 + cc];
    }
    __syncthreads();

    // wave q covers K-chunk [64q,64q+64); lane = (ir K-subsplit, c4 cols)
    float acc[5][4] = {};
#pragma unroll 4
    for (int ii = 0; ii < 16; ++ii) {
      int i = q * 64 + 4 * ii + ir;
      float4 sv = *(const float4*)&Slds[i * 64 + c4];  // b128 LDS
#pragma unroll
      for (int s = 0; s < 5; ++s) {
        float lv = lsb[s * ORD + i];  // broadcast
        acc[s][0] = fmaf(lv, sv.x, acc[s][0]);
        acc[s][1] = fmaf(lv, sv.y, acc[s][1]);
        acc[s][2] = fmaf(lv, sv.z, acc[s][2]);
        acc[s][3] = fmaf(lv, sv.w, acc[s][3]);
      }
    }
#pragma unroll
    for (int s = 0; s < 5; ++s)
#pragma unroll
      for (int w = 0; w < 4; ++w) {
        acc[s][w] += __shfl_xor(acc[s][w], 16);
        acc[s][w] += __shfl_xor(acc[s][w], 32);
      }
    if (ir == 0) {
#pragma unroll
      for (int s = 0; s < 5; ++s)
        *(float4*)&redb[q * 320 + s * 64 + c4] =
            make_float4(acc[s][0], acc[s][1], acc[s][2], acc[s][3]);
    }
    __syncthreads();
    for (int o = tid; o < 320; o += 256) {
      int s = o >> 6, c = o & 63;
      if (s < nrows) {
        float sum = redb[o] + redb[320 + o] + redb[640 + o] + redb[960 + o];
        if (s < 4) {
          ST_A(&Snew[(4 * rg + s) * ORD + cg * 64 + c], sum);
        } else {
          ST_A(&P[(half + rg) * ORD + cg * 64 + c], sum);
        }
      }
    }
    gbar(flags, (unsigned)(k + 1));
  }

  // ---------- out: Gs = sum_{j<64} U[255-j-64s] (x) P[j] (wave s = q),
  // then Horner: out = G0 + (G1 + (G2 + G3@A64)@A64)@A64 ----------
  {
    float* Garr = Slds;         // [4][8][256] G segments (chain S-slice dead)
    float* redo = Slds + 8192;  // [4][8][256] Horner K-split partials
    const float* A64 = ws + OFF_AP + 5 * APSTRIDE;
    const int bm0 = blk * 8;
    const int c4o = lane * 4;

    for (int idx = tid; idx < SEQ_T * 8; idx += 256) {
      int t = idx >> 3, r = idx & 7;
      us[idx] = U[t * BMROWS + bm0 + r];  // first touch of U cols
    }
    __syncthreads();

    // G-accum: wave q owns segment q; 64 j-terms (same FMA as R6 out loop)
    float acc[8][4] = {};
#pragma unroll 4
    for (int j = 0; j < 64; ++j) {
      float4 pv = *(const float4*)&P[j * ORD + c4o];  // L2-hot, 64 KB total
      int t = 255 - 64 * q - j;
      float4 u0 = *(const float4*)&us[t * 8];  // LDS broadcast
      float4 u1 = *(const float4*)&us[t * 8 + 4];
      float uv[8] = {u0.x, u0.y, u0.z, u0.w, u1.x, u1.y, u1.z, u1.w};
      float pw[4] = {pv.x, pv.y, pv.z, pv.w};
#pragma unroll
      for (int r = 0; r < 8; ++r)
#pragma unroll
        for (int w = 0; w < 4; ++w)
          acc[r][w] = fmaf(uv[r], pw[w], acc[r][w]);
    }
#pragma unroll
    for (int r = 0; r < 8; ++r)
      *(float4*)&Garr[q * 2048 + r * 256 + c4o] =
          make_float4(acc[r][0], acc[r][1], acc[r][2], acc[r][3]);
    __syncthreads();

    // Horner: T <- T@A64 + G_s for s = 2,1,0 (T starts as G3 = Garr[3]).
    // K-split across waves (A64 read once per block per mult, L2-hot).
    for (int s = 2; s >= 0; --s) {
      const float* T = &Garr[(s + 1) * 2048];
      float hl[8][4] = {};
#pragma unroll 4
      for (int ii = 0; ii < 64; ++ii) {
        int i = q * 64 + ii;
        float4 av = *(const float4*)&A64[i * ORD + c4o];  // b128 coalesced
        float tv[8];
#pragma unroll
        for (int r = 0; r < 8; ++r) tv[r] = T[r * 256 + i];  // LDS broadcast
#pragma unroll
        for (int r = 0; r < 8; ++r) {
          hl[r][0] = fmaf(tv[r], av.x, hl[r][0]);
          hl[r][1] = fmaf(tv[r], av.y, hl[r][1]);
          hl[r][2] = fmaf(tv[r], av.z, hl[r][2]);
          hl[r][3] = fmaf(tv[r], av.w, hl[r][3]);
        }
      }
#pragma unroll
      for (int r = 0; r < 8; ++r)
        *(float4*)&redo[q * 2048 + r * 256 + c4o] =
            make_float4(hl[r][0], hl[r][1], hl[r][2], hl[r][3]);
      __syncthreads();
      const int c = tid;
#pragma unroll
      for (int r = 0; r < 8; ++r) {
        float v = redo[r * 256 + c] + redo[2048 + r * 256 + c] +
                  redo[4096 + r * 256 + c] + redo[6144 + r * 256 + c] +
                  Garr[s * 2048 + r * 256 + c];
        if (s > 0)
          Garr[s * 2048 + r * 256 + c] = v;  // becomes next T
        else
          out[(bm0 + r) * ORD + c] = v;  // coalesced final store
      }
      __syncthreads();
    }
  }
}

extern "C" void kernel_launch(void* const* d_in, const int* in_sizes, int n_in,
                              void* d_out, int out_size, void* d_ws,
                              size_t ws_size, hipStream_t stream) {
  const float* x = (const float*)d_in[0];   // (16,256,128)
  const float* K = (const float*)d_in[1];   // (128,128)
  const float* A = (const float*)d_in[2];   // (256,256)
  const float* Bm = (const float*)d_in[3];  // (256,)
  float* out = (float*)d_out;               // (16, 32768)
  float* ws = (float*)d_ws;

  // zero barrier flags + gen (ws re-poisoned 0xAA before every timed call)
  hipMemsetAsync(ws + OFF_FLAGS, 0, 2048, stream);
  lrmu_all<<<256, 256, 0, stream>>>(x, K, A, Bm, out, ws);
}